// Round 7
// baseline (58.257 us; speedup 1.0000x reference)
//
#include <hip/hip_runtime.h>
#include <hip/hip_bf16.h>

typedef __attribute__((ext_vector_type(4))) float f32x4;
typedef __attribute__((ext_vector_type(8))) short bf16x8;

#define N_NEI 64
#define D_IN  128
#define D_HID 128

union BF8 { bf16x8 v; __hip_bfloat162 h[4]; unsigned u[4]; };

__device__ __forceinline__ bf16x8 pack8(const float4& a, const float4& b) {
  BF8 r;
  r.h[0] = __float22bfloat162_rn(float2{a.x, a.y});
  r.h[1] = __float22bfloat162_rn(float2{a.z, a.w});
  r.h[2] = __float22bfloat162_rn(float2{b.x, b.y});
  r.h[3] = __float22bfloat162_rn(float2{b.z, b.w});
  return r.v;
}

// Fused kernel: per block (4 waves), for 4 batch rows:
//  Phase A (pooling, round-5 structure verbatim — best measured):
//    pooled[r][j] = max_n relu(neigh[r,n,:]·W_mlp[j,:] + b_mlp[j]), masked n -> 0
//    each wave owns one batch row; result kept in LDS pscr (fp32).
//  Phase B (combine, fused former k2):
//    out[r][:] = relu(concat(input[r], pooled[r]) · W_comb^T + b_comb)
//    one 16-row M-tile (rows lr&3 duplicated; rows 4-15 computed, not stored),
//    B-fragments read directly from fp32 W_comb (L2-hot, 256KB shared by all
//    blocks), A from input(global) + pscr(LDS). No second kernel, no pooled
//    global round-trip, no grid-wide dependency.
__global__ __launch_bounds__(256, 2)
void fused_pool_comb(const float* __restrict__ inp, const float* __restrict__ neigh,
                     const float* __restrict__ Wmlp, const float* __restrict__ bmlp,
                     const float* __restrict__ Wcomb, const float* __restrict__ bcomb,
                     float* __restrict__ out) {
  __shared__ unsigned short Wl[D_HID * D_IN];  // 32KB bf16, row j = 256B, XOR-swizzled
  __shared__ float pscr[4][132];               // pooled fp32; 132 = pad to break banks

  const int tid = threadIdx.x;
  const int l = tid & 63;
  const int w = tid >> 6;
  const int lr = l & 15;   // A row-in-tile / B col-in-tile
  const int lg = l >> 4;   // k-group

  const int b0 = blockIdx.x * 4;
  const int b = b0 + w;                 // this wave's batch row
  const float* rowbase = neigh + (size_t)b * N_NEI * D_IN;

  // ---- Phase A: pooling (round-5 code) ----
  // 0. issue tile-0 neighbor loads first — overlap with W staging below
  float4 pf[8];
  {
    const float* arow = rowbase + (size_t)lr * D_IN + lg * 8;
    #pragma unroll
    for (int ks = 0; ks < 4; ++ks) {
      pf[2 * ks]     = *(const float4*)(arow + ks * 32);
      pf[2 * ks + 1] = *(const float4*)(arow + ks * 32 + 4);
    }
  }

  // 1. stage W_mlp -> LDS bf16 (swizzled: byte = j*256 + ((d*2) ^ ((j&7)<<4)))
  const float4* W4 = (const float4*)Wmlp;
  #pragma unroll
  for (int it = 0; it < 8; ++it) {
    int f8 = it * 256 + tid;            // 8-float chunk id, 0..2047
    int j  = f8 >> 4;                   // row 0..127
    int d0 = (f8 & 15) * 8;             // col start
    float4 a = W4[f8 * 2];
    float4 bb = W4[f8 * 2 + 1];
    int byte = j * 256 + ((d0 * 2) ^ ((j & 7) << 4));
    *(bf16x8*)((char*)Wl + byte) = pack8(a, bb);
  }

  float bml[8];
  #pragma unroll
  for (int t = 0; t < 8; ++t) bml[t] = bmlp[t * 16 + lr];

  __syncthreads();   // drains staging (and pf) — pf ready at loop entry

  float pmax[8];
  #pragma unroll
  for (int t = 0; t < 8; ++t) pmax[t] = 0.f;  // exact: masked entries are 0, relu >= 0

  #pragma unroll 1
  for (int mt = 0; mt < 4; ++mt) {      // 16-neighbor M-tile, one at a time
    // 2. consume pf: fp32->bf16 fragments + fp32 row-sum for the mask
    bf16x8 af[4];
    float rs = 0.f;
    #pragma unroll
    for (int ks = 0; ks < 4; ++ks) {
      float4 a0 = pf[2 * ks];
      float4 a1 = pf[2 * ks + 1];
      rs += a0.x + a0.y + a0.z + a0.w + a1.x + a1.y + a1.z + a1.w;
      af[ks] = pack8(a0, a1);
    }

    // 3. issue next tile's loads — in flight under the MFMA section
    if (mt < 3) {
      const float* arow = rowbase + (size_t)((mt + 1) * 16 + lr) * D_IN + lg * 8;
      #pragma unroll
      for (int ks = 0; ks < 4; ++ks) {
        pf[2 * ks]     = *(const float4*)(arow + ks * 32);
        pf[2 * ks + 1] = *(const float4*)(arow + ks * 32 + 4);
      }
    }

    rs += __shfl_xor(rs, 16);
    rs += __shfl_xor(rs, 32);   // full fp32 row sum of neighbor (mt*16+lr)
    unsigned mask16 = (unsigned)(__ballot(rs == 0.0f) & 0xFFFFull);

    // 4. two passes of 4 N-tiles: halves accumulator live-range (anti-spill)
    #pragma unroll 1
    for (int p = 0; p < 2; ++p) {
      f32x4 acc[4];
      #pragma unroll
      for (int tt = 0; tt < 4; ++tt) acc[tt] = (f32x4){0.f, 0.f, 0.f, 0.f};

      #pragma unroll
      for (int tt = 0; tt < 4; ++tt) {
        #pragma unroll
        for (int ks = 0; ks < 4; ++ks) {
          int jr = (p * 4 + tt) * 16 + lr;
          int d0 = ks * 32 + lg * 8;
          bf16x8 bf = *(const bf16x8*)((const char*)Wl + jr * 256 + ((d0 * 2) ^ ((jr & 7) << 4)));
          acc[tt] = __builtin_amdgcn_mfma_f32_16x16x32_bf16(af[ks], bf, acc[tt], 0, 0, 0);
        }
      }

      #pragma unroll
      for (int tt = 0; tt < 4; ++tt) {
        #pragma unroll
        for (int r = 0; r < 4; ++r) {
          int row = lg * 4 + r;          // D-layout: row = (l>>4)*4 + reg
          float v = fmaxf(acc[tt][r] + bml[p * 4 + tt], 0.f);
          if ((mask16 >> row) & 1u) v = 0.f;
          pmax[p * 4 + tt] = fmaxf(pmax[p * 4 + tt], v);
        }
      }
    }
  }

  // cross-lane-group max (rows live in lg groups)
  #pragma unroll
  for (int t = 0; t < 8; ++t) {
    pmax[t] = fmaxf(pmax[t], __shfl_xor(pmax[t], 16));
    pmax[t] = fmaxf(pmax[t], __shfl_xor(pmax[t], 32));
  }

  // pooled -> LDS (fp32), wave w owns pscr[w]
  if (l < 16) {
    #pragma unroll
    for (int t = 0; t < 8; ++t) pscr[w][t * 16 + l] = pmax[t];
  }

  // ---- Phase B: combine (fused former k2) ----
  // A-frag input half: issue global loads before the barrier (independent of pscr)
  const int ar = b0 + (lr & 3);         // rows 4-15 duplicate 0-3 (unused, no OOB)
  bf16x8 caf[8];
  {
    const float* p = inp + (size_t)ar * D_IN + lg * 8;
    #pragma unroll
    for (int ks = 0; ks < 4; ++ks) {
      float4 a0 = *(const float4*)(p + ks * 32);
      float4 a1 = *(const float4*)(p + ks * 32 + 4);
      caf[ks] = pack8(a0, a1);
    }
  }

  __syncthreads();   // pscr visible to all waves

  // A-frag pooled half from pscr (fp32, padded rows -> ~2-way banks)
  #pragma unroll
  for (int ks = 0; ks < 4; ++ks) {
    const float* p = &pscr[lr & 3][ks * 32 + lg * 8];
    float4 a0 = *(const float4*)p;
    float4 a1 = *(const float4*)(p + 4);
    caf[4 + ks] = pack8(a0, a1);
  }

  // each wave computes 4 N-tiles = 64 output cols; B straight from L2-hot W_comb
  #pragma unroll 1
  for (int nt = 0; nt < 4; ++nt) {
    const int jr = w * 64 + nt * 16 + lr;     // W_comb row = output col
    const float* wp = Wcomb + (size_t)jr * 256;
    f32x4 acc = (f32x4){0.f, 0.f, 0.f, 0.f};
    #pragma unroll
    for (int ks = 0; ks < 8; ++ks) {
      float4 w0 = *(const float4*)(wp + ks * 32 + lg * 8);
      float4 w1 = *(const float4*)(wp + ks * 32 + lg * 8 + 4);
      acc = __builtin_amdgcn_mfma_f32_16x16x32_bf16(caf[ks], pack8(w0, w1), acc, 0, 0, 0);
    }
    float bc = bcomb[jr];
    if (lg == 0) {                            // rows 0-3 are the real batch rows
      #pragma unroll
      for (int r = 0; r < 4; ++r) {
        out[(size_t)(b0 + r) * 256 + jr] = fmaxf(acc[r] + bc, 0.f);
      }
    }
  }
}

extern "C" void kernel_launch(void* const* d_in, const int* in_sizes, int n_in,
                              void* d_out, int out_size, void* d_ws, size_t ws_size,
                              hipStream_t stream) {
  const float* inp   = (const float*)d_in[0];
  const float* neigh = (const float*)d_in[1];
  const float* Wmlp  = (const float*)d_in[2];
  const float* bmlp  = (const float*)d_in[3];
  const float* Wcomb = (const float*)d_in[4];
  const float* bcomb = (const float*)d_in[5];
  float* out = (float*)d_out;

  fused_pool_comb<<<1024, 256, 0, stream>>>(inp, neigh, Wmlp, bmlp, Wcomb, bcomb, out);
}

// Round 8
// 36.753 us; speedup vs baseline: 1.5851x; 1.5851x over previous
//
#include <hip/hip_runtime.h>
#include <hip/hip_bf16.h>

typedef __attribute__((ext_vector_type(4))) float f32x4;
typedef __attribute__((ext_vector_type(8))) short bf16x8;

#define N_NEI 64
#define D_IN  128
#define D_HID 128

union BF8 { bf16x8 v; __hip_bfloat162 h[4]; unsigned u[4]; };

__device__ __forceinline__ bf16x8 pack8(const float4& a, const float4& b) {
  BF8 r;
  r.h[0] = __float22bfloat162_rn(float2{a.x, a.y});
  r.h[1] = __float22bfloat162_rn(float2{a.z, a.w});
  r.h[2] = __float22bfloat162_rn(float2{b.x, b.y});
  r.h[3] = __float22bfloat162_rn(float2{b.z, b.w});
  return r.v;
}

// Kernel 1: pooled[b][j] = max_n relu(neigh[b,n,:]·W_mlp[j,:] + b_mlp[j]), masked rows -> 0.
// One block = 4 waves; each wave owns ONE batch row (all 64 neighbors).
// Round-7 lesson (counters): latency-bound (MfmaUtil 5.5%, VALU 28%, occ 35%),
// L3 serves ~half the neigh traffic (FETCH 66MB). Lever: DUAL M-TILE —
// 32 rows/iteration, each B-fragment LDS read feeds TWO MFMAs. Halves LDS
// traffic (128->64 KB/wave) + conflicts, doubles MFMA ILP per load window,
// 2 iterations instead of 4. pf[16] one-deep prefetch retained.
__global__ __launch_bounds__(256, 2)
void k1_pool(const float* __restrict__ neigh, const float* __restrict__ Wmlp,
             const float* __restrict__ bmlp, unsigned short* __restrict__ pooled) {
  __shared__ unsigned short Wl[D_HID * D_IN];  // 32KB bf16, row j = 256B, XOR-swizzled
  __shared__ float pscr[4][D_HID];             // per-wave epilogue scratch

  const int tid = threadIdx.x;
  const int l = tid & 63;
  const int w = tid >> 6;
  const int lr = l & 15;   // A row-in-tile / B col-in-tile
  const int lg = l >> 4;   // k-group

  const int b = blockIdx.x * 4 + w;     // this wave's batch row
  const float* rowbase = neigh + (size_t)b * N_NEI * D_IN;

  // 0. issue iter-0's 32-row loads first — overlap with W staging below
  //    pf[0..7] = row lr, pf[8..15] = row lr+16
  float4 pf[16];
  {
    const float* ra = rowbase + (size_t)lr * D_IN + lg * 8;
    const float* rb = rowbase + (size_t)(16 + lr) * D_IN + lg * 8;
    #pragma unroll
    for (int ks = 0; ks < 4; ++ks) {
      pf[2 * ks]      = *(const float4*)(ra + ks * 32);
      pf[2 * ks + 1]  = *(const float4*)(ra + ks * 32 + 4);
      pf[8 + 2 * ks]  = *(const float4*)(rb + ks * 32);
      pf[9 + 2 * ks]  = *(const float4*)(rb + ks * 32 + 4);
    }
  }

  // 1. stage W_mlp -> LDS bf16 (swizzled: byte = j*256 + ((d*2) ^ ((j&7)<<4)))
  const float4* W4 = (const float4*)Wmlp;
  #pragma unroll
  for (int it = 0; it < 8; ++it) {
    int f8 = it * 256 + tid;            // 8-float chunk id, 0..2047
    int j  = f8 >> 4;                   // row 0..127
    int d0 = (f8 & 15) * 8;             // col start
    float4 a = W4[f8 * 2];
    float4 bb = W4[f8 * 2 + 1];
    int byte = j * 256 + ((d0 * 2) ^ ((j & 7) << 4));
    *(bf16x8*)((char*)Wl + byte) = pack8(a, bb);
  }

  float bml[8];
  #pragma unroll
  for (int t = 0; t < 8; ++t) bml[t] = bmlp[t * 16 + lr];

  __syncthreads();   // drains staging (and pf) — pf ready at loop entry

  float pmax[8];
  #pragma unroll
  for (int t = 0; t < 8; ++t) pmax[t] = 0.f;  // exact: masked entries are 0, relu >= 0

  #pragma unroll 1
  for (int it = 0; it < 2; ++it) {      // 32-neighbor dual M-tile per iteration
    // 2. consume pf: fp32->bf16 fragments + fp32 row-sums for the mask
    bf16x8 afA[4], afB[4];
    float rsA = 0.f, rsB = 0.f;
    #pragma unroll
    for (int ks = 0; ks < 4; ++ks) {
      float4 a0 = pf[2 * ks],     a1 = pf[2 * ks + 1];
      float4 b0 = pf[8 + 2 * ks], b1 = pf[9 + 2 * ks];
      rsA += a0.x + a0.y + a0.z + a0.w + a1.x + a1.y + a1.z + a1.w;
      rsB += b0.x + b0.y + b0.z + b0.w + b1.x + b1.y + b1.z + b1.w;
      afA[ks] = pack8(a0, a1);
      afB[ks] = pack8(b0, b1);
    }

    // 3. issue iter-1's loads — in flight under this iteration's MFMA section
    if (it == 0) {
      const float* ra = rowbase + (size_t)(32 + lr) * D_IN + lg * 8;
      const float* rb = rowbase + (size_t)(48 + lr) * D_IN + lg * 8;
      #pragma unroll
      for (int ks = 0; ks < 4; ++ks) {
        pf[2 * ks]      = *(const float4*)(ra + ks * 32);
        pf[2 * ks + 1]  = *(const float4*)(ra + ks * 32 + 4);
        pf[8 + 2 * ks]  = *(const float4*)(rb + ks * 32);
        pf[9 + 2 * ks]  = *(const float4*)(rb + ks * 32 + 4);
      }
    }

    rsA += __shfl_xor(rsA, 16); rsA += __shfl_xor(rsA, 32);
    rsB += __shfl_xor(rsB, 16); rsB += __shfl_xor(rsB, 32);
    unsigned maskA = (unsigned)(__ballot(rsA == 0.0f) & 0xFFFFull);
    unsigned maskB = (unsigned)(__ballot(rsB == 0.0f) & 0xFFFFull);

    // 4. two passes of 4 N-tiles; each B read feeds both M-tiles
    #pragma unroll 1
    for (int p = 0; p < 2; ++p) {
      f32x4 accA[4], accB[4];
      #pragma unroll
      for (int tt = 0; tt < 4; ++tt) {
        accA[tt] = (f32x4){0.f, 0.f, 0.f, 0.f};
        accB[tt] = (f32x4){0.f, 0.f, 0.f, 0.f};
      }

      #pragma unroll
      for (int tt = 0; tt < 4; ++tt) {
        #pragma unroll
        for (int ks = 0; ks < 4; ++ks) {
          int jr = (p * 4 + tt) * 16 + lr;
          int d0 = ks * 32 + lg * 8;
          bf16x8 bf = *(const bf16x8*)((const char*)Wl + jr * 256 + ((d0 * 2) ^ ((jr & 7) << 4)));
          accA[tt] = __builtin_amdgcn_mfma_f32_16x16x32_bf16(afA[ks], bf, accA[tt], 0, 0, 0);
          accB[tt] = __builtin_amdgcn_mfma_f32_16x16x32_bf16(afB[ks], bf, accB[tt], 0, 0, 0);
        }
      }

      // relu + bias + mask, fold into running per-lane max
      #pragma unroll
      for (int tt = 0; tt < 4; ++tt) {
        #pragma unroll
        for (int r = 0; r < 4; ++r) {
          int row = lg * 4 + r;          // D-layout: row = (l>>4)*4 + reg
          float vA = fmaxf(accA[tt][r] + bml[p * 4 + tt], 0.f);
          float vB = fmaxf(accB[tt][r] + bml[p * 4 + tt], 0.f);
          if ((maskA >> row) & 1u) vA = 0.f;
          if ((maskB >> row) & 1u) vB = 0.f;
          pmax[p * 4 + tt] = fmaxf(pmax[p * 4 + tt], fmaxf(vA, vB));
        }
      }
    }
  }

  // cross-lane-group max (rows live in lg groups)
  #pragma unroll
  for (int t = 0; t < 8; ++t) {
    pmax[t] = fmaxf(pmax[t], __shfl_xor(pmax[t], 16));
    pmax[t] = fmaxf(pmax[t], __shfl_xor(pmax[t], 32));
  }

  // epilogue: transpose via per-wave LDS scratch, packed bf16x2 store (256B/wave)
  if (l < 16) {
    #pragma unroll
    for (int t = 0; t < 8; ++t) pscr[w][t * 16 + l] = pmax[t];
  }
  __syncthreads();   // once per kernel; also orders pscr write->read
  float2 pv = *(const float2*)&pscr[w][2 * l];
  __hip_bfloat162 h2 = __float22bfloat162_rn(pv);
  ((unsigned*)(pooled + (size_t)b * D_HID))[l] = *(unsigned*)&h2;
}

// Kernel 2: out[b][j] = relu([input|pooled][b,:]·W_comb[j,:] + b_comb[j])
// Block = 64 rows x 64 cols (quarter of output cols), K = 256.  (round-5 verbatim)
__global__ __launch_bounds__(256, 2)
void k2_comb(const float* __restrict__ inp, const unsigned short* __restrict__ pooled,
             const float* __restrict__ Wcomb, const float* __restrict__ bcomb,
             float* __restrict__ out) {
  __shared__ unsigned short Wl[64 * 256];  // 32KB: 64 output cols x K=256, row = 512B, swizzled

  const int tid = threadIdx.x;
  const int l = tid & 63;
  const int w = tid >> 6;
  const int mchunk = blockIdx.x >> 2;   // 64-row chunk, 0..63
  const int colq   = blockIdx.x & 3;    // 64-col quarter
  const int lr = l & 15;
  const int lg = l >> 4;

  const int row = mchunk * 64 + w * 16 + lr;

  // 0. issue A loads first — overlap with W staging
  float4 a0[4], a1[4];
  #pragma unroll
  for (int ks = 0; ks < 4; ++ks) {   // k < 128: fp32 input
    const float* p = inp + (size_t)row * 128 + ks * 32 + lg * 8;
    a0[ks] = *(const float4*)p;
    a1[ks] = *(const float4*)(p + 4);
  }
  bf16x8 af[8];
  #pragma unroll
  for (int ks = 4; ks < 8; ++ks) {   // k >= 128: pooled already bf16
    af[ks] = *(const bf16x8*)(pooled + (size_t)row * 128 + (ks - 4) * 32 + lg * 8);
  }

  // 1. stage W quarter -> LDS bf16 (swizzled)
  const float4* W4 = (const float4*)Wcomb;
  #pragma unroll
  for (int it = 0; it < 8; ++it) {
    int c  = it * 256 + tid;            // 8-float chunk, 0..2047
    int jr = c >> 5;                    // 0..63
    int d0 = (c & 31) * 8;
    int gidx = ((colq * 64 + jr) * 256 + d0) >> 2;  // float4 index into W_comb
    float4 a = W4[gidx];
    float4 bb = W4[gidx + 1];
    int byte = jr * 512 + ((d0 * 2) ^ ((jr & 7) << 4));
    *(bf16x8*)((char*)Wl + byte) = pack8(a, bb);
  }

  float bcl[4];
  #pragma unroll
  for (int t = 0; t < 4; ++t) bcl[t] = bcomb[colq * 64 + t * 16 + lr];

  #pragma unroll
  for (int ks = 0; ks < 4; ++ks) af[ks] = pack8(a0[ks], a1[ks]);

  __syncthreads();

  f32x4 acc[4];
  #pragma unroll
  for (int t = 0; t < 4; ++t) acc[t] = (f32x4){0.f, 0.f, 0.f, 0.f};
  #pragma unroll
  for (int t = 0; t < 4; ++t) {
    #pragma unroll
    for (int ks = 0; ks < 8; ++ks) {
      int jr = t * 16 + lr;
      int d0 = ks * 32 + lg * 8;
      bf16x8 bf = *(const bf16x8*)((const char*)Wl + jr * 512 + ((d0 * 2) ^ ((jr & 7) << 4)));
      acc[t] = __builtin_amdgcn_mfma_f32_16x16x32_bf16(af[ks], bf, acc[t], 0, 0, 0);
    }
  }

  #pragma unroll
  for (int t = 0; t < 4; ++t) {
    #pragma unroll
    for (int r = 0; r < 4; ++r) {
      int ro = mchunk * 64 + w * 16 + lg * 4 + r;
      int co = colq * 64 + t * 16 + lr;
      float v = acc[t][r] + bcl[t];
      out[(size_t)ro * 256 + co] = fmaxf(v, 0.f);
    }
  }
}

extern "C" void kernel_launch(void* const* d_in, const int* in_sizes, int n_in,
                              void* d_out, int out_size, void* d_ws, size_t ws_size,
                              hipStream_t stream) {
  const float* inp   = (const float*)d_in[0];
  const float* neigh = (const float*)d_in[1];
  const float* Wmlp  = (const float*)d_in[2];
  const float* bmlp  = (const float*)d_in[3];
  const float* Wcomb = (const float*)d_in[4];
  const float* bcomb = (const float*)d_in[5];
  float* out = (float*)d_out;
  unsigned short* pooled = (unsigned short*)d_ws;  // [4096][128] bf16, 1 MB

  k1_pool<<<1024, 256, 0, stream>>>(neigh, Wmlp, bmlp, pooled);
  k2_comb<<<256, 256, 0, stream>>>(inp, pooled, Wcomb, bcomb, out);
}